// Round 1
// baseline (312.279 us; speedup 1.0000x reference)
//
#include <hip/hip_runtime.h>
#include <math.h>

#define N 8192
#define M 8192
#define KEEP 4096

// out layout (floats):
//   [0,        16384)   important_coords (4096 x 4)
//   [16384,    98304)   important_voxels (4096 x 5 x 4)
//   [98304,   102400)   kept_importance  (4096 x 1)
//   [102400,  110592)   importance       (8192 x 1)

__device__ __forceinline__ float safe_exp(float x) {
    // expf(-inf) = 0, but (-inf) - (-inf) = nan; callers guard that case.
    return expf(x);
}

// Kernel A: batch-masked attention over key coords + tiny MLP -> importance.
// grid 256 blocks x 256 threads; block handles 32 queries x 8 key-slices.
__global__ __launch_bounds__(256) void importance_kernel(
    const int*   __restrict__ vcoords,   // N x 4 int32 [b,z,y,x]
    const float* __restrict__ kcoords,   // M x 4 f32   [b,z,y,x]
    const float* __restrict__ w1,        // 3 x 32 row-major
    const float* __restrict__ b1,        // 32
    const float* __restrict__ w2,        // 32
    const float* __restrict__ b2,        // 1
    float* __restrict__ imp_ws,          // N scratch
    float* __restrict__ out_imp)         // N (d_out + 102400)
{
    __shared__ float4 sk[2048];          // 32 KB key tile

    const int t  = threadIdx.x;
    const int ql = t >> 3;               // local query 0..31
    const int sl = t & 7;                // key slice  0..7
    const int qi = blockIdx.x * 32 + ql;

    const int4 vc = ((const int4*)vcoords)[qi];
    const float qb = (float)vc.x;
    const float qz = (float)vc.y;
    const float qy = (float)vc.z;
    const float qx = (float)vc.w;
    const float inv_sqrt3 = 0.57735026918962576f;

    float m = -INFINITY, l = 0.f, sz = 0.f, sy = 0.f, sx = 0.f;

    for (int tile = 0; tile < M; tile += 2048) {
        __syncthreads();
        const float4* src = (const float4*)kcoords + tile;
        #pragma unroll
        for (int j = t; j < 2048; j += 256) sk[j] = src[j];
        __syncthreads();

        // interleaved slice indexing: lanes sl=0..7 read consecutive float4s
        // -> conflict-free LDS (broadcast across the 8 query-groups).
        for (int jj = sl; jj < 2048; jj += 8) {
            float4 k4 = sk[jj];
            if (k4.x == qb) {
                float s = (qz * k4.y + qy * k4.z + qx * k4.w) * inv_sqrt3;
                float nm = fmaxf(m, s);
                float a  = (m == -INFINITY) ? 0.f : safe_exp(m - nm);
                float e  = safe_exp(s - nm);
                l  = l  * a + e;
                sz = sz * a + e * k4.y;
                sy = sy * a + e * k4.z;
                sx = sx * a + e * k4.w;
                m  = nm;
            }
        }
    }

    // merge 8 slice states (lanes ql*8 .. ql*8+7, contiguous within a wave)
    #pragma unroll
    for (int off = 1; off < 8; off <<= 1) {
        float om = __shfl_xor(m,  off);
        float ol = __shfl_xor(l,  off);
        float oz = __shfl_xor(sz, off);
        float oy = __shfl_xor(sy, off);
        float ox = __shfl_xor(sx, off);
        float nm = fmaxf(m, om);
        float a  = (m  == -INFINITY) ? 0.f : safe_exp(m  - nm);
        float bb = (om == -INFINITY) ? 0.f : safe_exp(om - nm);
        l  = l  * a + ol * bb;
        sz = sz * a + oz * bb;
        sy = sy * a + oy * bb;
        sx = sx * a + ox * bb;
        m  = nm;
    }

    if (sl == 0) {
        float inv = (l > 0.f) ? 1.f / l : 0.f;
        float cz = sz * inv, cy = sy * inv, cx = sx * inv;
        float logit = b2[0];
        #pragma unroll
        for (int k = 0; k < 32; ++k) {
            float h = b1[k] + cz * w1[k] + cy * w1[32 + k] + cx * w1[64 + k];
            h = fmaxf(h, 0.f);
            logit += h * w2[k];
        }
        float p = 1.f / (1.f + expf(-logit));
        imp_ws[qi]  = p;
        out_imp[qi] = p;
    }
}

// Kernel B: stable-argsort rank via pairwise counting, then scatter.
// rank(i) = #{j: imp[j] < imp[i]} + #{j < i: imp[j] == imp[i]}
// keep iff rank >= KEEP, output row p = rank - KEEP  (matches jnp stable argsort)
__global__ __launch_bounds__(256) void rank_scatter_kernel(
    const float* __restrict__ imp,       // N
    const int*   __restrict__ vcoords,   // N x 4
    const float* __restrict__ voxels,    // N x 5 x 4
    float* __restrict__ out)
{
    __shared__ float simp[N];            // 32 KB
    const int t = threadIdx.x;
    for (int j = t; j < N; j += 256) simp[j] = imp[j];
    __syncthreads();

    const int ql = t >> 3;
    const int sl = t & 7;
    const int i  = blockIdx.x * 32 + ql;
    const float my = simp[i];

    int less = 0, eqlo = 0;
    for (int j = sl; j < N; j += 8) {    // interleaved: conflict-free broadcast
        float v = simp[j];
        less += (v < my) ? 1 : 0;
        eqlo += ((v == my) && (j < i)) ? 1 : 0;
    }
    #pragma unroll
    for (int off = 1; off < 8; off <<= 1) {
        less += __shfl_xor(less, off);
        eqlo += __shfl_xor(eqlo, off);
    }

    if (sl == 0) {
        int rank = less + eqlo;
        if (rank >= KEEP) {
            int p = rank - KEEP;
            int4 vc = ((const int4*)vcoords)[i];
            float* cdst = out + p * 4;
            cdst[0] = (float)vc.x;
            cdst[1] = (float)vc.y;
            cdst[2] = (float)vc.z;
            cdst[3] = (float)vc.w;
            const float* vsrc = voxels + i * 20;
            float* vdst = out + 16384 + p * 20;
            #pragma unroll
            for (int k = 0; k < 20; ++k) vdst[k] = vsrc[k];
            out[98304 + p] = my;
        }
    }
}

extern "C" void kernel_launch(void* const* d_in, const int* in_sizes, int n_in,
                              void* d_out, int out_size, void* d_ws, size_t ws_size,
                              hipStream_t stream) {
    const int*   vcoords = (const int*)d_in[0];
    const float* kcoords = (const float*)d_in[1];
    const float* voxels  = (const float*)d_in[2];
    const float* w1      = (const float*)d_in[3];
    const float* b1      = (const float*)d_in[4];
    const float* w2      = (const float*)d_in[5];
    const float* b2      = (const float*)d_in[6];
    float* out    = (float*)d_out;
    float* imp_ws = (float*)d_ws;

    importance_kernel<<<256, 256, 0, stream>>>(vcoords, kcoords, w1, b1, w2, b2,
                                               imp_ws, out + 102400);
    rank_scatter_kernel<<<256, 256, 0, stream>>>(imp_ws, vcoords, voxels, out);
}

// Round 2
// 160.862 us; speedup vs baseline: 1.9413x; 1.9413x over previous
//
#include <hip/hip_runtime.h>
#include <math.h>

#define N 8192
#define M 8192
#define KEEP 4096
#define QPB 8      // queries per block
#define SL  32     // key-slices per query (lanes per query group)

// out layout (floats):
//   [0,        16384)   important_coords (4096 x 4)
//   [16384,    98304)   important_voxels (4096 x 5 x 4)
//   [98304,   102400)   kept_importance  (4096 x 1)
//   [102400,  110592)   importance       (8192 x 1)

// Kernel A: two-pass batch-masked softmax-attention over key coords + MLP.
// Pass 1: masked max of dot (no exp, no serial chain).
// Pass 2: exp only for keys within 90 (score units) of the max — exactly the
// terms that are representable in the reference's own fp32 softmax sum; the
// argmax key contributes exp(0)=1 exactly, reproducing the one-hot result.
__global__ __launch_bounds__(256) void importance_kernel(
    const int*   __restrict__ vcoords,   // N x 4 int32 [b,z,y,x]
    const float* __restrict__ kcoords,   // M x 4 f32   [b,z,y,x]
    const float* __restrict__ w1,        // 3 x 32 row-major
    const float* __restrict__ b1,        // 32
    const float* __restrict__ w2,        // 32
    const float* __restrict__ b2,        // 1
    float* __restrict__ imp_ws,          // N scratch
    float* __restrict__ out_imp)         // N (d_out + 102400)
{
    const int t  = threadIdx.x;
    const int ql = t >> 5;               // local query 0..7
    const int sl = t & 31;               // key slice  0..31
    const int qi = blockIdx.x * QPB + ql;

    const int4 vc = ((const int4*)vcoords)[qi];
    const float qb = (float)vc.x;
    const float qz = (float)vc.y;
    const float qy = (float)vc.z;
    const float qx = (float)vc.w;
    const float inv_sqrt3 = 0.57735026918962576f;

    const float4* kc = (const float4*)kcoords;

    // ---- pass 1: masked max of dot ----
    float mx = -INFINITY;
    #pragma unroll 8
    for (int j = sl; j < M; j += SL) {
        float4 k4 = kc[j];
        float dot = fmaf(qz, k4.y, fmaf(qy, k4.z, qx * k4.w));
        mx = fmaxf(mx, (k4.x == qb) ? dot : -INFINITY);
    }
    #pragma unroll
    for (int off = 1; off < SL; off <<= 1)
        mx = fmaxf(mx, __shfl_xor(mx, off));

    // ---- pass 2: exp only near the max ----
    float l = 0.f, sz = 0.f, sy = 0.f, sx = 0.f;
    if (mx != -INFINITY) {
        // 90 in score units -> 90*sqrt(3) in dot units; terms below this are
        // sub-ulp (exp < 4e-40) in the reference's fp32 sum.
        const float cutoff = mx - 155.8845727f;
        #pragma unroll 4
        for (int j = sl; j < M; j += SL) {
            float4 k4 = kc[j];
            float dot = fmaf(qz, k4.y, fmaf(qy, k4.z, qx * k4.w));
            if (k4.x == qb && dot >= cutoff) {
                float e = expf((dot - mx) * inv_sqrt3);
                l  += e;
                sz = fmaf(e, k4.y, sz);
                sy = fmaf(e, k4.z, sy);
                sx = fmaf(e, k4.w, sx);
            }
        }
    }
    #pragma unroll
    for (int off = 1; off < SL; off <<= 1) {
        l  += __shfl_xor(l,  off);
        sz += __shfl_xor(sz, off);
        sy += __shfl_xor(sy, off);
        sx += __shfl_xor(sx, off);
    }

    if (sl == 0) {
        float inv = (l > 0.f) ? 1.f / l : 0.f;
        float cz = sz * inv, cy = sy * inv, cx = sx * inv;
        float logit = b2[0];
        #pragma unroll
        for (int k = 0; k < 32; ++k) {
            float h = b1[k] + cz * w1[k] + cy * w1[32 + k] + cx * w1[64 + k];
            h = fmaxf(h, 0.f);
            logit += h * w2[k];
        }
        float p = 1.f / (1.f + expf(-logit));
        imp_ws[qi]  = p;
        out_imp[qi] = p;
    }
}

// Kernel B: stable-argsort rank via pairwise counting, then scatter.
// rank(i) = #{j: imp[j] < imp[i]} + #{j < i: imp[j] == imp[i]}
// keep iff rank >= KEEP, output row p = rank - KEEP (== jnp stable argsort).
__global__ __launch_bounds__(256) void rank_scatter_kernel(
    const float* __restrict__ imp,       // N
    const int*   __restrict__ vcoords,   // N x 4
    const float* __restrict__ voxels,    // N x 5 x 4
    float* __restrict__ out)
{
    __shared__ float4 sf[N / 4];         // 32 KB
    const int t = threadIdx.x;
    const float4* g4 = (const float4*)imp;
    #pragma unroll
    for (int j = t; j < N / 4; j += 256) sf[j] = g4[j];
    __syncthreads();

    const int ql = t >> 5;
    const int sl = t & 31;
    const int i  = blockIdx.x * QPB + ql;
    const float my = ((const float*)sf)[i];

    int less = 0, eqlo = 0;
    #pragma unroll 4
    for (int jj = sl; jj < N / 4; jj += SL) {
        float4 v = sf[jj];
        int j = jj << 2;
        less += (v.x < my) ? 1 : 0;
        less += (v.y < my) ? 1 : 0;
        less += (v.z < my) ? 1 : 0;
        less += (v.w < my) ? 1 : 0;
        eqlo += ((v.x == my) && (j + 0 < i)) ? 1 : 0;
        eqlo += ((v.y == my) && (j + 1 < i)) ? 1 : 0;
        eqlo += ((v.z == my) && (j + 2 < i)) ? 1 : 0;
        eqlo += ((v.w == my) && (j + 3 < i)) ? 1 : 0;
    }
    #pragma unroll
    for (int off = 1; off < SL; off <<= 1) {
        less += __shfl_xor(less, off);
        eqlo += __shfl_xor(eqlo, off);
    }

    if (sl == 0) {
        int rank = less + eqlo;
        if (rank >= KEEP) {
            int p = rank - KEEP;
            int4 vc = ((const int4*)vcoords)[i];
            float4 c;
            c.x = (float)vc.x; c.y = (float)vc.y;
            c.z = (float)vc.z; c.w = (float)vc.w;
            *(float4*)(out + p * 4) = c;
            const float4* vs = (const float4*)(voxels + i * 20);
            float4* vd = (float4*)(out + 16384 + p * 20);
            #pragma unroll
            for (int k = 0; k < 5; ++k) vd[k] = vs[k];
            out[98304 + p] = my;
        }
    }
}

extern "C" void kernel_launch(void* const* d_in, const int* in_sizes, int n_in,
                              void* d_out, int out_size, void* d_ws, size_t ws_size,
                              hipStream_t stream) {
    const int*   vcoords = (const int*)d_in[0];
    const float* kcoords = (const float*)d_in[1];
    const float* voxels  = (const float*)d_in[2];
    const float* w1      = (const float*)d_in[3];
    const float* b1      = (const float*)d_in[4];
    const float* w2      = (const float*)d_in[5];
    const float* b2      = (const float*)d_in[6];
    float* out    = (float*)d_out;
    float* imp_ws = (float*)d_ws;

    importance_kernel<<<N / QPB, 256, 0, stream>>>(vcoords, kcoords, w1, b1, w2, b2,
                                                   imp_ws, out + 102400);
    rank_scatter_kernel<<<N / QPB, 256, 0, stream>>>(imp_ws, vcoords, voxels, out);
}

// Round 3
// 154.398 us; speedup vs baseline: 2.0226x; 1.0419x over previous
//
#include <hip/hip_runtime.h>
#include <math.h>

#define N 8192
#define M 8192
#define KEEP 4096
#define TILE 2048

// ws layout (float offsets):
//   [0,16)            header ints: kc0, kc1, qc0, qc1
//   [16, 16+4M)       partitioned keys  (batch0 first kc0 float4s, then batch1)
//   [16+4M, 16+8M)    partitioned query float4s {z,y,x,idx_bits} (batch0 then 1)
//   [16+8M, +2N)      K u64 array: (bits(imp)<<32)|idx   (byte-aligned to 8)
#define WS_KP   16
#define WS_QP   (WS_KP + 4*M)
#define WS_K64  (WS_QP + 4*N)

// out layout (floats):
//   [0,16384) coords | [16384,98304) voxels | [98304,102400) kept_imp
//   [102400,110592) importance

// ---------------------------------------------------------------- partition
__global__ __launch_bounds__(1024) void partition_kernel(
    const int4*   __restrict__ vcoords,
    const float4* __restrict__ kcoords,
    float* __restrict__ ws)
{
    __shared__ int wtot[16];
    const int t = threadIdx.x, w = t >> 6, lane = t & 63;
    const int base = t * 8;
    int* hdr = (int*)ws;
    float4* kp = (float4*)(ws + WS_KP);
    float4* qp = (float4*)(ws + WS_QP);

    // ---- keys ----
    float4 kv[8];
    int n0 = 0;
    #pragma unroll
    for (int r = 0; r < 8; ++r) { kv[r] = kcoords[base + r]; n0 += (kv[r].x == 0.0f) ? 1 : 0; }
    int inc = n0;
    #pragma unroll
    for (int off = 1; off < 64; off <<= 1) { int a = __shfl_up(inc, off); if (lane >= off) inc += a; }
    if (lane == 63) wtot[w] = inc;
    __syncthreads();
    int wbase = 0, tot0 = 0;
    #pragma unroll
    for (int i = 0; i < 16; ++i) { if (i < w) wbase += wtot[i]; tot0 += wtot[i]; }
    int ex0 = wbase + inc - n0;          // batch-0 keys strictly before me
    int ex1 = tot0 + (base - ex0);       // batch-1 region starts at tot0
    #pragma unroll
    for (int r = 0; r < 8; ++r) {
        if (kv[r].x == 0.0f) kp[ex0++] = kv[r]; else kp[ex1++] = kv[r];
    }
    if (t == 0) { hdr[0] = tot0; hdr[1] = M - tot0; }
    __syncthreads();                      // protect wtot reuse

    // ---- queries ----
    int4 qv[8];
    int qn0 = 0;
    #pragma unroll
    for (int r = 0; r < 8; ++r) { qv[r] = vcoords[base + r]; qn0 += (qv[r].x == 0) ? 1 : 0; }
    int qinc = qn0;
    #pragma unroll
    for (int off = 1; off < 64; off <<= 1) { int a = __shfl_up(qinc, off); if (lane >= off) qinc += a; }
    if (lane == 63) wtot[w] = qinc;
    __syncthreads();
    int qwbase = 0, qtot0 = 0;
    #pragma unroll
    for (int i = 0; i < 16; ++i) { if (i < w) qwbase += wtot[i]; qtot0 += wtot[i]; }
    int qex0 = qwbase + qinc - qn0;
    int qex1 = qtot0 + (base - qex0);
    #pragma unroll
    for (int r = 0; r < 8; ++r) {
        int idx = base + r;
        float4 q;
        q.x = (float)qv[r].y; q.y = (float)qv[r].z; q.z = (float)qv[r].w;
        q.w = __int_as_float(idx);
        if (qv[r].x == 0) qp[qex0++] = q; else qp[qex1++] = q;
    }
    if (t == 0) { hdr[2] = qtot0; hdr[3] = N - qtot0; }
}

// ---------------------------------------------------------------- attention
// block = 16 waves over the SAME 64 queries (lane = query), wave w = key-slice.
// Keys staged tile-wise in LDS; inner reads are wave-uniform -> broadcast.
__global__ __launch_bounds__(1024) void importance_kernel(
    float* __restrict__ ws,
    const float* __restrict__ w1, const float* __restrict__ b1,
    const float* __restrict__ w2, const float* __restrict__ b2,
    float* __restrict__ out_imp)
{
    __shared__ float4 sk[TILE];          // 32 KB
    __shared__ float red[5][16][64];     // 20 KB

    const int* hdr = (const int*)ws;
    const int qc0 = hdr[2], qc1 = hdr[3];
    const int ng0 = (qc0 + 63) >> 6;
    const int ng1 = (qc1 + 63) >> 6;

    const int bid = blockIdx.x;
    int batch, g;
    if (bid < ng0)            { batch = 0; g = bid; }
    else if (bid - ng0 < ng1) { batch = 1; g = bid - ng0; }
    else return;

    const int kc0 = hdr[0];
    const int kc  = batch ? hdr[1] : kc0;
    const int qc  = batch ? qc1 : qc0;
    const float4* kp = (const float4*)(ws + WS_KP) + (batch ? kc0 : 0);
    const float4* qp = (const float4*)(ws + WS_QP) + (batch ? qc0 : 0);

    const int t = threadIdx.x;
    const int w = t >> 6;
    const int lane = t & 63;

    const int qslot = g * 64 + lane;
    const bool valid = qslot < qc;
    float4 q4 = qp[valid ? qslot : 0];
    const float qz = q4.x, qy = q4.y, qx = q4.z;
    const int qidx = __float_as_int(q4.w);
    const float inv_sqrt3 = 0.57735026918962576f;

    // ---- pass 1: max of dot over this batch's keys ----
    float mx = -INFINITY;
    for (int tb = 0; tb < kc; tb += TILE) {
        const int tn = min(TILE, kc - tb);
        __syncthreads();
        for (int j = t; j < tn; j += 1024) sk[j] = kp[tb + j];
        __syncthreads();
        const int jb = w * (TILE / 16);
        const int je = min(jb + (TILE / 16), tn);
        #pragma unroll 8
        for (int j = jb; j < je; ++j) {
            float4 k4 = sk[j];
            float dot = fmaf(qz, k4.y, fmaf(qy, k4.z, qx * k4.w));
            mx = fmaxf(mx, dot);
        }
    }
    red[0][w][lane] = mx;
    __syncthreads();
    #pragma unroll
    for (int i = 0; i < 16; ++i) mx = fmaxf(mx, red[0][i][lane]);

    // ---- pass 2: exp only near the max (same cutoff as round 2) ----
    float l = 0.f, szz = 0.f, syy = 0.f, sxx = 0.f;
    const float cutoff = mx - 155.8845727f;
    for (int tb = 0; tb < kc; tb += TILE) {
        const int tn = min(TILE, kc - tb);
        __syncthreads();
        for (int j = t; j < tn; j += 1024) sk[j] = kp[tb + j];
        __syncthreads();
        const int jb = w * (TILE / 16);
        const int je = min(jb + (TILE / 16), tn);
        #pragma unroll 4
        for (int j = jb; j < je; ++j) {
            float4 k4 = sk[j];
            float dot = fmaf(qz, k4.y, fmaf(qy, k4.z, qx * k4.w));
            bool take = (dot >= cutoff);
            if (__any(take)) {
                float e = take ? expf((dot - mx) * inv_sqrt3) : 0.f;
                l  += e;
                szz = fmaf(e, k4.y, szz);
                syy = fmaf(e, k4.z, syy);
                sxx = fmaf(e, k4.w, sxx);
            }
        }
    }
    red[1][w][lane] = l;
    red[2][w][lane] = szz;
    red[3][w][lane] = syy;
    red[4][w][lane] = sxx;
    __syncthreads();

    if (w == 0 && valid) {
        float L = 0.f, SZ = 0.f, SY = 0.f, SX = 0.f;
        #pragma unroll
        for (int i = 0; i < 16; ++i) {
            L  += red[1][i][lane];
            SZ += red[2][i][lane];
            SY += red[3][i][lane];
            SX += red[4][i][lane];
        }
        float inv = (L > 0.f) ? 1.f / L : 0.f;
        float cz = SZ * inv, cy = SY * inv, cx = SX * inv;
        float logit = b2[0];
        #pragma unroll
        for (int k = 0; k < 32; ++k) {
            float h = b1[k] + cz * w1[k] + cy * w1[32 + k] + cx * w1[64 + k];
            h = fmaxf(h, 0.f);
            logit += h * w2[k];
        }
        float p = 1.f / (1.f + expf(-logit));
        out_imp[qidx] = p;
        unsigned long long* K = (unsigned long long*)(ws + WS_K64);
        K[qidx] = ((unsigned long long)__float_as_uint(p) << 32) | (unsigned)qidx;
    }
}

// ------------------------------------------------------------- rank+scatter
// rank(i) = #{j: K_j < K_i}, K = (bits(imp)<<32)|idx  == stable argsort rank.
// block = 64 elements (lanes) x 16 j-slices (waves); K staged in LDS,
// inner reads wave-uniform -> broadcast, v_cmp_lt_u64 + addc per pair.
__global__ __launch_bounds__(1024) void rank_scatter_kernel(
    const float* __restrict__ ws,
    const int4*  __restrict__ vcoords,
    const float* __restrict__ voxels,
    float* __restrict__ out)
{
    __shared__ unsigned long long sK[N];   // 64 KB (reused for partials)
    const unsigned long long* K = (const unsigned long long*)(ws + WS_K64);
    const int t = threadIdx.x, w = t >> 6, lane = t & 63;

    for (int j = t; j < N; j += 1024) sK[j] = K[j];
    __syncthreads();

    const int e = blockIdx.x * 64 + lane;
    const unsigned long long Ki = sK[e];

    int cnt = 0;
    const int jb = w * (N / 16);
    #pragma unroll 8
    for (int j = jb; j < jb + (N / 16); ++j)
        cnt += (sK[j] < Ki) ? 1 : 0;

    __syncthreads();                       // all reads of sK done
    ((int*)sK)[w * 64 + lane] = cnt;
    __syncthreads();

    if (w == 0) {
        int rank = 0;
        #pragma unroll
        for (int i = 0; i < 16; ++i) rank += ((int*)sK)[i * 64 + lane];
        if (rank >= KEEP) {
            const int p = rank - KEEP;
            int4 vc = vcoords[e];
            float4 c;
            c.x = (float)vc.x; c.y = (float)vc.y; c.z = (float)vc.z; c.w = (float)vc.w;
            *(float4*)(out + p * 4) = c;
            const float4* vs = (const float4*)(voxels + e * 20);
            float4* vd = (float4*)(out + 16384 + p * 20);
            #pragma unroll
            for (int k = 0; k < 5; ++k) vd[k] = vs[k];
            out[98304 + p] = __uint_as_float((unsigned)(Ki >> 32));
        }
    }
}

extern "C" void kernel_launch(void* const* d_in, const int* in_sizes, int n_in,
                              void* d_out, int out_size, void* d_ws, size_t ws_size,
                              hipStream_t stream) {
    const int4*   vcoords = (const int4*)d_in[0];
    const float4* kcoords = (const float4*)d_in[1];
    const float*  voxels  = (const float*)d_in[2];
    const float*  w1      = (const float*)d_in[3];
    const float*  b1      = (const float*)d_in[4];
    const float*  w2      = (const float*)d_in[5];
    const float*  b2      = (const float*)d_in[6];
    float* out = (float*)d_out;
    float* ws  = (float*)d_ws;

    partition_kernel<<<1, 1024, 0, stream>>>(vcoords, kcoords, ws);
    // 130 >= ceil(qc0/64)+ceil(qc1/64) for any split; extra blocks exit early
    importance_kernel<<<130, 1024, 0, stream>>>(ws, w1, b1, w2, b2, out + 102400);
    rank_scatter_kernel<<<N / 64, 1024, 0, stream>>>(ws, vcoords, voxels, out);
}